// Round 7
// baseline (381.817 us; speedup 1.0000x reference)
//
#include <hip/hip_runtime.h>
#include <math.h>

#define N_NODES 50000
#define N_EDGES 800000
#define EP      (N_EDGES + N_NODES)   // edges incl. self loops
#define IN_CH   128
#define HIDC    32
#define HEADS   4
#define OUTC    10
#define NGRAPH  64
#define NEG_SLOPE 0.2f
#define NPAD    50176                  // 128-row padded node count
#define NPART   8
#define PRNG    (N_NODES / NPART)      // 6250 nodes per partition

typedef unsigned int uint;
typedef __attribute__((ext_vector_type(8))) short bf16x8;
typedef __attribute__((ext_vector_type(4))) float f32x4;

__device__ __forceinline__ float lrelu(float x) { return x > 0.f ? x : NEG_SLOPE * x; }
__device__ __forceinline__ float eluf(float x)  { return x > 0.f ? x : __expf(x) - 1.f; }

__device__ __forceinline__ uint bfr(float f) {                 // f32 -> bf16 bits (RNE)
    uint a = __float_as_uint(f);
    return (a + 0x7FFFu + ((a >> 16) & 1u)) >> 16;
}
__device__ __forceinline__ uint bfpair(float lo, float hi) { return bfr(lo) | (bfr(hi) << 16); }
__device__ __forceinline__ float bflo(uint d) { return __uint_as_float(d << 16); }
__device__ __forceinline__ float bfhi(uint d) { return __uint_as_float(d & 0xFFFF0000u); }

// ---------------- CSR build (dst-range partitioned: blockIdx%8 ~ XCD) ----------------
__global__ __launch_bounds__(256) void k_count(const int* __restrict__ dst, int* __restrict__ indeg) {
    int part = blockIdx.x & (NPART - 1);
    int base = (blockIdx.x >> 3) * 2048;
    int lo = part * PRNG;
#pragma unroll
    for (int it = 0; it < 8; ++it) {
        int e = base + it * 256 + threadIdx.x;
        if (e < N_EDGES) {
            int d = dst[e];
            if ((uint)(d - lo) < PRNG) atomicAdd(&indeg[d], 1);
        }
    }
}

// ---------------- fused: single-block scan (csr/pos) + attention-weight prep ----------------
__global__ __launch_bounds__(1024) void k_scanprep(const int* __restrict__ indeg,
                                                   int* __restrict__ csr, int* __restrict__ pos,
                                                   const float* __restrict__ W1,
                                                   const float* __restrict__ a1s, const float* __restrict__ a1d,
                                                   const float* __restrict__ W2,
                                                   const float* __restrict__ a2s, const float* __restrict__ a2d,
                                                   float* __restrict__ w_als, float* __restrict__ w2v) {
    int t = threadIdx.x;
    // ---- wprep: w_als[u], u = ch*8 + j ----
    {
        int i = t >> 3, j = t & 7, head = j & 3;
        const float* vec = (j < 4) ? a1s : a1d;
        float s = 0.f;
        for (int c = 0; c < 32; ++c)
            s += W1[i * 128 + head * 32 + c] * vec[head * 32 + c];
        w_als[t] = s;
    }
    if (t < 256) {
        int i = t >> 1, j = t & 1;
        const float* vec = j ? a2d : a2s;
        float s = 0.f;
        for (int c = 0; c < 32; ++c)
            s += W2[i * 32 + c] * vec[c];
        w2v[i * 2 + j] = s;
    }
    // ---- scan of (indeg[i]+1) over 50000 nodes, 49 nodes/thread ----
    const int PER = 49;
    int base = t * PER;
    int sum = 0;
    for (int k = 0; k < PER; ++k) {
        int i = base + k;
        if (i < N_NODES) sum += indeg[i] + 1;
    }
    __shared__ int bs[1024];
    bs[t] = sum; __syncthreads();
    for (int off = 1; off < 1024; off <<= 1) {
        int v = (t >= off) ? bs[t - off] : 0;
        __syncthreads();
        bs[t] += v;
        __syncthreads();
    }
    int run = (t == 0) ? 0 : bs[t - 1];
    for (int k = 0; k < PER; ++k) {
        int i = base + k;
        if (i < N_NODES) {
            csr[i] = run; pos[i] = run;
            run += indeg[i] + 1;
        }
    }
    if (t == 1023) csr[N_NODES] = bs[1023];
}

__global__ __launch_bounds__(256) void k_scatter(const int* __restrict__ src, const int* __restrict__ dst,
                                                 int* __restrict__ pos, int* __restrict__ esrc) {
    int part = blockIdx.x & (NPART - 1);
    int base = (blockIdx.x >> 3) * 2048;
    int lo = part * PRNG;
#pragma unroll
    for (int it = 0; it < 8; ++it) {
        int e = base + it * 256 + threadIdx.x;
        if (e < EP) {
            int d = (e < N_EDGES) ? dst[e] : (e - N_EDGES);
            if ((uint)(d - lo) < PRNG) {
                int s = (e < N_EDGES) ? src[e] : d;
                int p = atomicAdd(&pos[d], 1);
                esrc[p] = s;
            }
        }
    }
}

// ---------------- cvt: x -> bf16 xb, + conv1 logits (f32, via x . (W1 a)) ----------------
__global__ __launch_bounds__(256) void k_cvt(const float* __restrict__ x,
                                             const float* __restrict__ w_als,
                                             uint2* __restrict__ xb2,
                                             float* __restrict__ als1, float* __restrict__ ald1) {
    __shared__ float wc[1024];          // column-major: wc[j*128 + ch]
    int t = threadIdx.x;
    for (int u = t; u < 1024; u += 256) {
        int ch = u >> 3, j = u & 7;
        wc[j * 128 + ch] = w_als[u];
    }
    __syncthreads();
    int n = blockIdx.x * 8 + (t >> 5);
    int cp = t & 31;
    float4 xv = *(const float4*)&x[n * 128 + cp * 4];
    xb2[n * 32 + cp] = make_uint2(bfpair(xv.x, xv.y), bfpair(xv.z, xv.w));
    float p[8];
#pragma unroll
    for (int j = 0; j < 8; ++j) {
        float4 w = *(const float4*)&wc[j * 128 + cp * 4];
        p[j] = xv.x * w.x + xv.y * w.y + xv.z * w.z + xv.w * w.w;
    }
#pragma unroll
    for (int off = 1; off < 32; off <<= 1) {
#pragma unroll
        for (int j = 0; j < 8; ++j) p[j] += __shfl_xor(p[j], off);
    }
    if (cp == 0) {
        float4 s = {p[0], p[1], p[2], p[3]};
        float4 d = {p[4], p[5], p[6], p[7]};
        *(float4*)&als1[n * 4] = s;
        *(float4*)&ald1[n * 4] = d;
    }
}

// ---------------- GEMM1 (MFMA): h1b = bf16( xb @ (W1hi+W1lo) ), dword w = chs (w, w+64) ----------------
__global__ __launch_bounds__(256) void k_gemm1(const uint4* __restrict__ xb4,
                                               const float* __restrict__ W,
                                               uint* __restrict__ h1b) {
    __shared__ uint4 WH[2048];          // Wt_hi[n][k] swizzled, 32 KB
    __shared__ uint4 WL[2048];          // Wt_lo
    int t = threadIdx.x;
    uint* whw = (uint*)WH;
    uint* wlw = (uint*)WL;
    for (int it = 0; it < 16; ++it) {
        int u = it * 256 + t;
        int n = u & 127, kq = u >> 7;   // kq: 4-wide k group (0..31)
        float w0 = W[(kq * 4 + 0) * 128 + n];
        float w1 = W[(kq * 4 + 1) * 128 + n];
        float w2 = W[(kq * 4 + 2) * 128 + n];
        float w3 = W[(kq * 4 + 3) * 128 + n];
        uint h0 = bfr(w0), h1 = bfr(w1), h2 = bfr(w2), h3 = bfr(w3);
        float l0 = w0 - __uint_as_float(h0 << 16);
        float l1 = w1 - __uint_as_float(h1 << 16);
        float l2 = w2 - __uint_as_float(h2 << 16);
        float l3 = w3 - __uint_as_float(h3 << 16);
        int word = n * 64 + (((kq >> 1) ^ (n & 7)) << 2) + (kq & 1) * 2;
        *(uint2*)&whw[word] = make_uint2(h0 | (h1 << 16), h2 | (h3 << 16));
        *(uint2*)&wlw[word] = make_uint2(bfr(l0) | (bfr(l1) << 16), bfr(l2) | (bfr(l3) << 16));
    }
    __syncthreads();
    int l = t & 63, wid = t >> 6;
    int lr = l & 15, lg = l >> 4;
    int rowb = blockIdx.x * 128 + wid * 32;
    f32x4 acc[2][8] = {};
#pragma unroll
    for (int ks = 0; ks < 4; ++ks) {
        uint4 av0 = xb4[(rowb + lr) * 16 + ks * 4 + lg];
        uint4 av1 = xb4[(rowb + 16 + lr) * 16 + ks * 4 + lg];
        bf16x8 a0 = *reinterpret_cast<bf16x8*>(&av0);
        bf16x8 a1 = *reinterpret_cast<bf16x8*>(&av1);
        int quw = ks * 4 + lg;
#pragma unroll
        for (int nt = 0; nt < 8; ++nt) {
            int n = nt * 16 + lr;
            int idx = n * 16 + (quw ^ (n & 7));
            bf16x8 bh = *reinterpret_cast<bf16x8*>(&WH[idx]);
            bf16x8 bl = *reinterpret_cast<bf16x8*>(&WL[idx]);
            acc[0][nt] = __builtin_amdgcn_mfma_f32_16x16x32_bf16(a0, bh, acc[0][nt], 0, 0, 0);
            acc[0][nt] = __builtin_amdgcn_mfma_f32_16x16x32_bf16(a0, bl, acc[0][nt], 0, 0, 0);
            acc[1][nt] = __builtin_amdgcn_mfma_f32_16x16x32_bf16(a1, bh, acc[1][nt], 0, 0, 0);
            acc[1][nt] = __builtin_amdgcn_mfma_f32_16x16x32_bf16(a1, bl, acc[1][nt], 0, 0, 0);
        }
    }
#pragma unroll
    for (int mt = 0; mt < 2; ++mt)
#pragma unroll
        for (int nt = 0; nt < 4; ++nt)
#pragma unroll
            for (int r = 0; r < 4; ++r) {
                int row = rowb + mt * 16 + 4 * lg + r;
                if (row < N_NODES)
                    h1b[row * 64 + nt * 16 + lr] = bfpair(acc[mt][nt][r], acc[mt][nt + 4][r]);
            }
}

// ---------------- agg1: chunked LDS weight cache, each exp computed ONCE ----------------
// phase A: lanes (eo=l>>2, h=l&3) compute weights for 16 edges/sweep into wave LDS.
// phase B: half-wave per edge, pure LDS-broadcast + gather + FMA.
__global__ __launch_bounds__(256) void k_agg1(const uint2* __restrict__ h1b2,
                                              const int* __restrict__ csr, const int* __restrict__ esrc,
                                              const float* __restrict__ als1, const float* __restrict__ ald1,
                                              const float* __restrict__ b1,
                                              const float* __restrict__ w2v,
                                              uint* __restrict__ o1b,
                                              float* __restrict__ als2, float* __restrict__ ald2) {
    __shared__ float wbuf[4][2][256];   // [wave][dbuf][64 edges x 4 heads] = 8 KB
    int l = threadIdx.x & 63;
    int wv = threadIdx.x >> 6;
    int n = blockIdx.x * 4 + wv;
    int s = csr[n], e = csr[n + 1];
    int h = l & 3, eo = l >> 2;
    int cp = l & 31, half = l >> 5, hh0 = cp >> 4;
    float adh = ald1[n * 4 + h];
    float acc0 = 0.f, acc1 = 0.f, acc2 = 0.f, acc3 = 0.f, ssum = 0.f;
    int buf = 0;
    for (int c0 = s; c0 < e; c0 += 64, buf ^= 1) {
        int cnt = min(64, e - c0);
        float* wb = wbuf[wv][buf];
        // phase A: weights (one exp per edge-head, ever)
        for (int j = eo; j < cnt; j += 16) {
            int sa = esrc[c0 + j];
            float wgt = __expf(lrelu(als1[sa * 4 + h] + adh));
            wb[j * 4 + h] = wgt;
            ssum += wgt;
        }
        // phase B: gather + FMA (weights broadcast from LDS)
        for (int i = c0 + half; i < c0 + cnt; i += 2) {
            int j4 = (i - c0) * 4;
            int sa = esrc[i];
            float w0 = wb[j4 + hh0];
            float w1 = wb[j4 + 2 + hh0];
            uint2 d = h1b2[sa * 32 + cp];
            acc0 += w0 * bflo(d.x); acc1 += w1 * bfhi(d.x);
            acc2 += w0 * bflo(d.y); acc3 += w1 * bfhi(d.y);
        }
    }
    // denominator: reduce over 16 lanes per head (lane = eo*4+h -> xor bits 2..5)
    ssum += __shfl_xor(ssum, 4);  ssum += __shfl_xor(ssum, 8);
    ssum += __shfl_xor(ssum, 16); ssum += __shfl_xor(ssum, 32);
    acc0 += __shfl_xor(acc0, 32); acc1 += __shfl_xor(acc1, 32);
    acc2 += __shfl_xor(acc2, 32); acc3 += __shfl_xor(acc3, 32);
    float inv0 = 1.f / __shfl(ssum, hh0);       // lanes 0..3 hold heads 0..3
    float inv1 = 1.f / __shfl(ssum, hh0 + 2);
    if (half == 0) {
        float2 bb0 = *(const float2*)&b1[2 * cp];
        float2 bb1 = *(const float2*)&b1[64 + 2 * cp];
        float v00 = eluf(acc0 * inv0 + bb0.x);   // ch 2cp
        float v01 = eluf(acc2 * inv0 + bb0.y);   // ch 2cp+1
        float v10 = eluf(acc1 * inv1 + bb1.x);   // ch 2cp+64
        float v11 = eluf(acc3 * inv1 + bb1.y);   // ch 2cp+65
        o1b[n * 64 + cp]      = bfpair(v00, v01);
        o1b[n * 64 + 32 + cp] = bfpair(v10, v11);
        const float4* w2v4 = (const float4*)w2v;
        float4 wv0 = w2v4[cp];        // [2cp][0..1],[2cp+1][0..1]
        float4 wv1 = w2v4[32 + cp];   // [2cp+64][0..1],[2cp+65][0..1]
        float p0 = v00 * wv0.x + v01 * wv0.z + v10 * wv1.x + v11 * wv1.z;
        float p1 = v00 * wv0.y + v01 * wv0.w + v10 * wv1.y + v11 * wv1.w;
#pragma unroll
        for (int off = 1; off < 32; off <<= 1) {
            p0 += __shfl_xor(p0, off);
            p1 += __shfl_xor(p1, off);
        }
        if (cp == 0) { als2[n] = p0; ald2[n] = p1; }
    }
}

// ---------------- GEMM2 (MFMA): h2b = bf16( o1b @ (W2hi+W2lo) ), dword w = chs (w, w+16) ----------------
__global__ __launch_bounds__(256) void k_gemm2(const uint4* __restrict__ ob4,
                                               const float* __restrict__ W,
                                               uint* __restrict__ h2b) {
    __shared__ uint4 WH[512];           // Wt_hi[n 0..31][k] swizzled, 8 KB
    __shared__ uint4 WL[512];
    int t = threadIdx.x;
    uint* whw = (uint*)WH;
    uint* wlw = (uint*)WL;
    for (int it = 0; it < 4; ++it) {
        int u = it * 256 + t;
        int n = u & 31, kq = u >> 5;
        float w0 = W[(kq * 4 + 0) * 32 + n];
        float w1 = W[(kq * 4 + 1) * 32 + n];
        float w2 = W[(kq * 4 + 2) * 32 + n];
        float w3 = W[(kq * 4 + 3) * 32 + n];
        uint h0 = bfr(w0), h1 = bfr(w1), h2 = bfr(w2), h3 = bfr(w3);
        float l0 = w0 - __uint_as_float(h0 << 16);
        float l1 = w1 - __uint_as_float(h1 << 16);
        float l2 = w2 - __uint_as_float(h2 << 16);
        float l3 = w3 - __uint_as_float(h3 << 16);
        int word = n * 64 + (((kq >> 1) ^ (n & 7)) << 2) + (kq & 1) * 2;
        *(uint2*)&whw[word] = make_uint2(h0 | (h1 << 16), h2 | (h3 << 16));
        *(uint2*)&wlw[word] = make_uint2(bfr(l0) | (bfr(l1) << 16), bfr(l2) | (bfr(l3) << 16));
    }
    __syncthreads();
    int l = t & 63, wid = t >> 6;
    int lr = l & 15, lg = l >> 4;
    int rowb = blockIdx.x * 128 + wid * 32;
    f32x4 acc[2][2] = {};
#pragma unroll
    for (int ks = 0; ks < 4; ++ks) {
        uint4 av0 = ob4[(rowb + lr) * 16 + ks * 4 + lg];
        uint4 av1 = ob4[(rowb + 16 + lr) * 16 + ks * 4 + lg];
        bf16x8 a0 = *reinterpret_cast<bf16x8*>(&av0);
        bf16x8 a1 = *reinterpret_cast<bf16x8*>(&av1);
        int quw = ks * 4 + lg;
#pragma unroll
        for (int nt = 0; nt < 2; ++nt) {
            int n = nt * 16 + lr;
            int idx = n * 16 + (quw ^ (n & 7));
            bf16x8 bh = *reinterpret_cast<bf16x8*>(&WH[idx]);
            bf16x8 bl = *reinterpret_cast<bf16x8*>(&WL[idx]);
            acc[0][nt] = __builtin_amdgcn_mfma_f32_16x16x32_bf16(a0, bh, acc[0][nt], 0, 0, 0);
            acc[0][nt] = __builtin_amdgcn_mfma_f32_16x16x32_bf16(a0, bl, acc[0][nt], 0, 0, 0);
            acc[1][nt] = __builtin_amdgcn_mfma_f32_16x16x32_bf16(a1, bh, acc[1][nt], 0, 0, 0);
            acc[1][nt] = __builtin_amdgcn_mfma_f32_16x16x32_bf16(a1, bl, acc[1][nt], 0, 0, 0);
        }
    }
#pragma unroll
    for (int mt = 0; mt < 2; ++mt)
#pragma unroll
        for (int r = 0; r < 4; ++r) {
            int row = rowb + mt * 16 + 4 * lg + r;
            if (row < N_NODES)
                h2b[row * 16 + lr] = bfpair(acc[mt][0][r], acc[mt][1][r]);
        }
}

// ---------------- agg2: chunked LDS weight cache, quarter-wave per edge ----------------
__global__ __launch_bounds__(256) void k_agg2(const uint* __restrict__ h2b,
                                              const int* __restrict__ csr, const int* __restrict__ esrc,
                                              const float* __restrict__ als, const float* __restrict__ ald,
                                              const float* __restrict__ b2,
                                              float* __restrict__ o2) {
    __shared__ float wbuf[4][2][64];    // 2 KB
    int l = threadIdx.x & 63;
    int wv = threadIdx.x >> 6;
    int n = blockIdx.x * 4 + wv;
    int s = csr[n], e = csr[n + 1];
    int cp = l & 15, sub = l >> 4;
    float ad = ald[n];
    float acc0 = 0.f, acc1 = 0.f, ssum = 0.f;
    int buf = 0;
    for (int c0 = s; c0 < e; c0 += 64, buf ^= 1) {
        int cnt = min(64, e - c0);
        float* wb = wbuf[wv][buf];
        for (int j = l; j < cnt; j += 64) {
            int sa = esrc[c0 + j];
            float wgt = __expf(lrelu(als[sa] + ad));
            wb[j] = wgt;
            ssum += wgt;
        }
        for (int i = c0 + sub; i < c0 + cnt; i += 4) {
            int sa = esrc[i];
            float wgt = wb[i - c0];
            uint d = h2b[sa * 16 + cp];
            acc0 += wgt * bflo(d); acc1 += wgt * bfhi(d);
        }
    }
#pragma unroll
    for (int off = 1; off < 64; off <<= 1) ssum += __shfl_xor(ssum, off);
    acc0 += __shfl_xor(acc0, 16); acc1 += __shfl_xor(acc1, 16);
    acc0 += __shfl_xor(acc0, 32); acc1 += __shfl_xor(acc1, 32);
    if (l < 16) {
        float inv = 1.f / ssum;
        o2[n * 32 + cp]      = eluf(acc0 * inv + b2[cp]);
        o2[n * 32 + 16 + cp] = eluf(acc1 * inv + b2[16 + cp]);
    }
}

// ---------------- fused pool + final linear (inline boundary search) ----------------
__global__ __launch_bounds__(256) void k_poolfinal(const float* __restrict__ out2,
                                                   const int* __restrict__ batch,
                                                   const float* __restrict__ Wl,
                                                   const float* __restrict__ bl,
                                                   float* __restrict__ out) {
    __shared__ float red[4][32];
    __shared__ float pooled[32];
    int g = blockIdx.x;
    int s = 0, hi = N_NODES;
    while (s < hi) { int mid = (s + hi) >> 1; if (batch[mid] < g) s = mid + 1; else hi = mid; }
    int e = s; hi = N_NODES;
    while (e < hi) { int mid = (e + hi) >> 1; if (batch[mid] < g + 1) e = mid + 1; else hi = mid; }
    int t = threadIdx.x;
    int c = t & 31, r = t >> 5;
    float acc = 0.f;
    for (int i = s + r; i < e; i += 8)
        acc += out2[i * 32 + c];
    acc += __shfl_xor(acc, 32);
    if ((t & 63) < 32) red[t >> 6][c] = acc;
    __syncthreads();
    if (t < 32) {
        float v = red[0][t] + red[1][t] + red[2][t] + red[3][t];
        float cnt = fmaxf((float)(e - s), 1.f);
        pooled[t] = v / cnt;
    }
    __syncthreads();
    if (t < OUTC) {
        float a = 0.f;
        for (int cc = 0; cc < HIDC; cc++)
            a += pooled[cc] * Wl[cc * OUTC + t];
        out[g * OUTC + t] = a + bl[t];
    }
}

extern "C" void kernel_launch(void* const* d_in, const int* in_sizes, int n_in,
                              void* d_out, int out_size, void* d_ws, size_t ws_size,
                              hipStream_t stream) {
    (void)in_sizes; (void)n_in; (void)out_size; (void)ws_size;
    const float* x    = (const float*)d_in[0];
    const int*   ei   = (const int*)d_in[1];
    const int*   srcA = ei;
    const int*   dstA = ei + N_EDGES;
    const int*   batch = (const int*)d_in[2];
    const float* W1  = (const float*)d_in[3];
    const float* a1s = (const float*)d_in[4];
    const float* a1d = (const float*)d_in[5];
    const float* b1  = (const float*)d_in[6];
    const float* W2  = (const float*)d_in[7];
    const float* a2s = (const float*)d_in[8];
    const float* a2d = (const float*)d_in[9];
    const float* b2  = (const float*)d_in[10];
    const float* Wl  = (const float*)d_in[11];
    const float* bl  = (const float*)d_in[12];
    float* out = (float*)d_out;

    char* w = (char*)d_ws;
    auto alloc = [&](size_t bytes) -> void* {
        void* p = (void*)w;
        w += (bytes + 255) & ~(size_t)255;
        return p;
    };
    uint*  xb   = (uint*)alloc((size_t)NPAD * 64 * 4);       // x bf16, 12.85 MB
    uint*  h1b  = (uint*)alloc((size_t)N_NODES * 64 * 4);    // 12.8 MB
    uint*  o1b  = (uint*)alloc((size_t)NPAD * 64 * 4);       // 12.85 MB
    uint*  h2b  = (uint*)alloc((size_t)N_NODES * 16 * 4);    // 3.2 MB
    float* o2   = (float*)alloc((size_t)N_NODES * 32 * 4);   // 6.4 MB
    float* als1 = (float*)alloc((size_t)N_NODES * 4 * 4);
    float* ald1 = (float*)alloc((size_t)N_NODES * 4 * 4);
    float* als2 = (float*)alloc((size_t)N_NODES * 4);
    float* ald2 = (float*)alloc((size_t)N_NODES * 4);
    float* w_als = (float*)alloc(1024 * 4);
    float* w2v   = (float*)alloc(256 * 4);
    int*   indeg = (int*)alloc((size_t)N_NODES * 4);
    int*   csr   = (int*)alloc((size_t)(N_NODES + 1) * 4);
    int*   pos   = (int*)alloc((size_t)N_NODES * 4);
    int*   esrc  = (int*)alloc((size_t)EP * 4);

    int ncc = (N_EDGES + 2047) / 2048;   // count chunks: 391
    int nsc = (EP + 2047) / 2048;        // scatter chunks: 416

    hipMemsetAsync(indeg, 0, (size_t)N_NODES * 4, stream);
    k_count<<<ncc * NPART, 256, 0, stream>>>(dstA, indeg);
    k_scanprep<<<1, 1024, 0, stream>>>(indeg, csr, pos, W1, a1s, a1d, W2, a2s, a2d, w_als, w2v);
    k_scatter<<<nsc * NPART, 256, 0, stream>>>(srcA, dstA, pos, esrc);
    k_cvt<<<N_NODES / 8, 256, 0, stream>>>(x, w_als, (uint2*)xb, als1, ald1);
    k_gemm1<<<NPAD / 128, 256, 0, stream>>>((const uint4*)xb, W1, h1b);
    k_agg1<<<N_NODES / 4, 256, 0, stream>>>((const uint2*)h1b, csr, esrc, als1, ald1, b1, w2v,
                                            o1b, als2, ald2);
    k_gemm2<<<NPAD / 128, 256, 0, stream>>>((const uint4*)o1b, W2, h2b);
    k_agg2<<<N_NODES / 4, 256, 0, stream>>>(h2b, csr, esrc, als2, ald2, b2, o2);
    k_poolfinal<<<NGRAPH, 256, 0, stream>>>(o2, batch, Wl, bl, out);
}

// Round 8
// 264.655 us; speedup vs baseline: 1.4427x; 1.4427x over previous
//
#include <hip/hip_runtime.h>
#include <math.h>

#define N_NODES 50000
#define N_EDGES 800000
#define EP      (N_EDGES + N_NODES)   // edges incl. self loops
#define IN_CH   128
#define HIDC    32
#define HEADS   4
#define OUTC    10
#define NGRAPH  64
#define NEG_SLOPE 0.2f
#define NPAD    50176                  // 128-row padded node count
#define NPART   8
#define PRNG    (N_NODES / NPART)      // 6250 nodes per partition

typedef unsigned int uint;
typedef __attribute__((ext_vector_type(8))) short bf16x8;
typedef __attribute__((ext_vector_type(4))) float f32x4;

__device__ __forceinline__ float lrelu(float x) { return x > 0.f ? x : NEG_SLOPE * x; }
__device__ __forceinline__ float eluf(float x)  { return x > 0.f ? x : __expf(x) - 1.f; }

__device__ __forceinline__ uint bfr(float f) {                 // f32 -> bf16 bits (RNE)
    uint a = __float_as_uint(f);
    return (a + 0x7FFFu + ((a >> 16) & 1u)) >> 16;
}
__device__ __forceinline__ uint bfpair(float lo, float hi) { return bfr(lo) | (bfr(hi) << 16); }
__device__ __forceinline__ float bflo(uint d) { return __uint_as_float(d << 16); }
__device__ __forceinline__ float bfhi(uint d) { return __uint_as_float(d & 0xFFFF0000u); }

// ---------------- CSR build (dst-range partitioned: blockIdx%8 ~ XCD) ----------------
__global__ __launch_bounds__(256) void k_count(const int* __restrict__ dst, int* __restrict__ indeg) {
    int part = blockIdx.x & (NPART - 1);
    int base = (blockIdx.x >> 3) * 2048;
    int lo = part * PRNG;
#pragma unroll
    for (int it = 0; it < 8; ++it) {
        int e = base + it * 256 + threadIdx.x;
        if (e < N_EDGES) {
            int d = dst[e];
            if ((uint)(d - lo) < PRNG) atomicAdd(&indeg[d], 1);
        }
    }
}

// ---------------- parallel 3-stage scan (196 blocks) ----------------
__global__ void k_scan1(const int* __restrict__ indeg, int* __restrict__ incl, int* __restrict__ bsum) {
    __shared__ int s[256];
    int t = threadIdx.x;
    int i = blockIdx.x * 256 + t;
    int v = (i < N_NODES) ? indeg[i] + 1 : 0;   // +1 self loop
    s[t] = v; __syncthreads();
    for (int off = 1; off < 256; off <<= 1) {
        int x = (t >= off) ? s[t - off] : 0;
        __syncthreads();
        s[t] += x;
        __syncthreads();
    }
    if (i < N_NODES) incl[i] = s[t];
    if (t == 255) bsum[blockIdx.x] = s[255];
}

__global__ void k_scan2(int* __restrict__ bsum, int nb) {
    __shared__ int s[256];
    int t = threadIdx.x;
    int v = (t < nb) ? bsum[t] : 0;
    s[t] = v; __syncthreads();
    for (int off = 1; off < 256; off <<= 1) {
        int x = (t >= off) ? s[t - off] : 0;
        __syncthreads();
        s[t] += x;
        __syncthreads();
    }
    if (t < nb) bsum[t] = s[t] - v;   // exclusive
}

__global__ void k_scan3(const int* __restrict__ indeg, int* __restrict__ csr,
                        const int* __restrict__ boff, int* __restrict__ pos) {
    int i = blockIdx.x * 256 + threadIdx.x;
    if (i >= N_NODES) return;
    int inc = csr[i] + boff[i >> 8];
    int ex = inc - indeg[i] - 1;
    csr[i] = ex;
    pos[i] = ex;
    if (i == N_NODES - 1) csr[N_NODES] = inc;
}

__global__ __launch_bounds__(256) void k_scatter(const int* __restrict__ src, const int* __restrict__ dst,
                                                 int* __restrict__ pos, int* __restrict__ esrc) {
    int part = blockIdx.x & (NPART - 1);
    int base = (blockIdx.x >> 3) * 2048;
    int lo = part * PRNG;
#pragma unroll
    for (int it = 0; it < 8; ++it) {
        int e = base + it * 256 + threadIdx.x;
        if (e < EP) {
            int d = (e < N_EDGES) ? dst[e] : (e - N_EDGES);
            if ((uint)(d - lo) < PRNG) {
                int s = (e < N_EDGES) ? src[e] : d;
                int p = atomicAdd(&pos[d], 1);
                esrc[p] = s;
            }
        }
    }
}

// ---------------- weight prep: w_als[u], u = ch*8 + j ; w2v[i][j] = W2 . a2 ----------------
__global__ void k_wprep(const float* __restrict__ W1,
                        const float* __restrict__ a1s, const float* __restrict__ a1d,
                        const float* __restrict__ W2,
                        const float* __restrict__ a2s, const float* __restrict__ a2d,
                        float* __restrict__ w_als, float* __restrict__ w2v) {
    int t = threadIdx.x;
    for (int it = 0; it < 4; ++it) {
        int u = it * 256 + t;           // 1024 units
        int i = u >> 3, j = u & 7;
        int head = j & 3;
        const float* vec = (j < 4) ? a1s : a1d;
        float s = 0.f;
        for (int c = 0; c < 32; ++c)
            s += W1[i * 128 + head * 32 + c] * vec[head * 32 + c];
        w_als[u] = s;
    }
    {
        int i = t >> 1, j = t & 1;
        const float* vec = j ? a2d : a2s;
        float s = 0.f;
        for (int c = 0; c < 32; ++c)
            s += W2[i * 32 + c] * vec[c];
        w2v[i * 2 + j] = s;
    }
}

// ---------------- cvt: x -> bf16 xb, + conv1 logits (f32, via x . (W1 a)) ----------------
__global__ __launch_bounds__(256) void k_cvt(const float* __restrict__ x,
                                             const float* __restrict__ w_als,
                                             uint2* __restrict__ xb2,
                                             float* __restrict__ als1, float* __restrict__ ald1) {
    __shared__ float wc[1024];          // column-major: wc[j*128 + ch]
    int t = threadIdx.x;
    for (int u = t; u < 1024; u += 256) {
        int ch = u >> 3, j = u & 7;
        wc[j * 128 + ch] = w_als[u];
    }
    __syncthreads();
    int n = blockIdx.x * 8 + (t >> 5);
    int cp = t & 31;
    float4 xv = *(const float4*)&x[n * 128 + cp * 4];
    xb2[n * 32 + cp] = make_uint2(bfpair(xv.x, xv.y), bfpair(xv.z, xv.w));
    float p[8];
#pragma unroll
    for (int j = 0; j < 8; ++j) {
        float4 w = *(const float4*)&wc[j * 128 + cp * 4];
        p[j] = xv.x * w.x + xv.y * w.y + xv.z * w.z + xv.w * w.w;
    }
#pragma unroll
    for (int off = 1; off < 32; off <<= 1) {
#pragma unroll
        for (int j = 0; j < 8; ++j) p[j] += __shfl_xor(p[j], off);
    }
    if (cp == 0) {
        float4 s = {p[0], p[1], p[2], p[3]};
        float4 d = {p[4], p[5], p[6], p[7]};
        *(float4*)&als1[n * 4] = s;
        *(float4*)&ald1[n * 4] = d;
    }
}

// ---------------- GEMM1 (MFMA): h1b = bf16( xb @ (W1hi+W1lo) ), dword w = chs (w, w+64) ----------------
__global__ __launch_bounds__(256) void k_gemm1(const uint4* __restrict__ xb4,
                                               const float* __restrict__ W,
                                               uint* __restrict__ h1b) {
    __shared__ uint4 WH[2048];          // Wt_hi[n][k] swizzled, 32 KB
    __shared__ uint4 WL[2048];          // Wt_lo
    int t = threadIdx.x;
    uint* whw = (uint*)WH;
    uint* wlw = (uint*)WL;
    for (int it = 0; it < 16; ++it) {
        int u = it * 256 + t;
        int n = u & 127, kq = u >> 7;   // kq: 4-wide k group (0..31)
        float w0 = W[(kq * 4 + 0) * 128 + n];
        float w1 = W[(kq * 4 + 1) * 128 + n];
        float w2 = W[(kq * 4 + 2) * 128 + n];
        float w3 = W[(kq * 4 + 3) * 128 + n];
        uint h0 = bfr(w0), h1 = bfr(w1), h2 = bfr(w2), h3 = bfr(w3);
        float l0 = w0 - __uint_as_float(h0 << 16);
        float l1 = w1 - __uint_as_float(h1 << 16);
        float l2 = w2 - __uint_as_float(h2 << 16);
        float l3 = w3 - __uint_as_float(h3 << 16);
        int word = n * 64 + (((kq >> 1) ^ (n & 7)) << 2) + (kq & 1) * 2;
        *(uint2*)&whw[word] = make_uint2(h0 | (h1 << 16), h2 | (h3 << 16));
        *(uint2*)&wlw[word] = make_uint2(bfr(l0) | (bfr(l1) << 16), bfr(l2) | (bfr(l3) << 16));
    }
    __syncthreads();
    int l = t & 63, wid = t >> 6;
    int lr = l & 15, lg = l >> 4;
    int rowb = blockIdx.x * 128 + wid * 32;
    f32x4 acc[2][8] = {};
#pragma unroll
    for (int ks = 0; ks < 4; ++ks) {
        uint4 av0 = xb4[(rowb + lr) * 16 + ks * 4 + lg];
        uint4 av1 = xb4[(rowb + 16 + lr) * 16 + ks * 4 + lg];
        bf16x8 a0 = *reinterpret_cast<bf16x8*>(&av0);
        bf16x8 a1 = *reinterpret_cast<bf16x8*>(&av1);
        int quw = ks * 4 + lg;
#pragma unroll
        for (int nt = 0; nt < 8; ++nt) {
            int n = nt * 16 + lr;
            int idx = n * 16 + (quw ^ (n & 7));
            bf16x8 bh = *reinterpret_cast<bf16x8*>(&WH[idx]);
            bf16x8 bl = *reinterpret_cast<bf16x8*>(&WL[idx]);
            acc[0][nt] = __builtin_amdgcn_mfma_f32_16x16x32_bf16(a0, bh, acc[0][nt], 0, 0, 0);
            acc[0][nt] = __builtin_amdgcn_mfma_f32_16x16x32_bf16(a0, bl, acc[0][nt], 0, 0, 0);
            acc[1][nt] = __builtin_amdgcn_mfma_f32_16x16x32_bf16(a1, bh, acc[1][nt], 0, 0, 0);
            acc[1][nt] = __builtin_amdgcn_mfma_f32_16x16x32_bf16(a1, bl, acc[1][nt], 0, 0, 0);
        }
    }
#pragma unroll
    for (int mt = 0; mt < 2; ++mt)
#pragma unroll
        for (int nt = 0; nt < 4; ++nt)
#pragma unroll
            for (int r = 0; r < 4; ++r) {
                int row = rowb + mt * 16 + 4 * lg + r;
                if (row < N_NODES)
                    h1b[row * 64 + nt * 16 + lr] = bfpair(acc[mt][nt][r], acc[mt][nt + 4][r]);
            }
}

// ---------------- agg1: chunked LDS weight cache, each exp computed ONCE ----------------
__global__ __launch_bounds__(256) void k_agg1(const uint2* __restrict__ h1b2,
                                              const int* __restrict__ csr, const int* __restrict__ esrc,
                                              const float* __restrict__ als1, const float* __restrict__ ald1,
                                              const float* __restrict__ b1,
                                              const float* __restrict__ w2v,
                                              uint* __restrict__ o1b,
                                              float* __restrict__ als2, float* __restrict__ ald2) {
    __shared__ float wbuf[4][2][256];   // [wave][dbuf][64 edges x 4 heads] = 8 KB
    int l = threadIdx.x & 63;
    int wv = threadIdx.x >> 6;
    int n = blockIdx.x * 4 + wv;
    int s = csr[n], e = csr[n + 1];
    int h = l & 3, eo = l >> 2;
    int cp = l & 31, half = l >> 5, hh0 = cp >> 4;
    float adh = ald1[n * 4 + h];
    float acc0 = 0.f, acc1 = 0.f, acc2 = 0.f, acc3 = 0.f, ssum = 0.f;
    int buf = 0;
    for (int c0 = s; c0 < e; c0 += 64, buf ^= 1) {
        int cnt = min(64, e - c0);
        float* wb = wbuf[wv][buf];
        // phase A: weights (one exp per edge-head, ever)
        for (int j = eo; j < cnt; j += 16) {
            int sa = esrc[c0 + j];
            float wgt = __expf(lrelu(als1[sa * 4 + h] + adh));
            wb[j * 4 + h] = wgt;
            ssum += wgt;
        }
        // phase B: gather + FMA (weights broadcast from LDS)
        for (int i = c0 + half; i < c0 + cnt; i += 2) {
            int j4 = (i - c0) * 4;
            int sa = esrc[i];
            float w0 = wb[j4 + hh0];
            float w1 = wb[j4 + 2 + hh0];
            uint2 d = h1b2[sa * 32 + cp];
            acc0 += w0 * bflo(d.x); acc1 += w1 * bfhi(d.x);
            acc2 += w0 * bflo(d.y); acc3 += w1 * bfhi(d.y);
        }
    }
    // denominator: reduce over 16 lanes per head (lane = eo*4+h -> xor bits 2..5)
    ssum += __shfl_xor(ssum, 4);  ssum += __shfl_xor(ssum, 8);
    ssum += __shfl_xor(ssum, 16); ssum += __shfl_xor(ssum, 32);
    acc0 += __shfl_xor(acc0, 32); acc1 += __shfl_xor(acc1, 32);
    acc2 += __shfl_xor(acc2, 32); acc3 += __shfl_xor(acc3, 32);
    float inv0 = 1.f / __shfl(ssum, hh0);       // lanes 0..3 hold heads 0..3
    float inv1 = 1.f / __shfl(ssum, hh0 + 2);
    if (half == 0) {
        float2 bb0 = *(const float2*)&b1[2 * cp];
        float2 bb1 = *(const float2*)&b1[64 + 2 * cp];
        float v00 = eluf(acc0 * inv0 + bb0.x);   // ch 2cp
        float v01 = eluf(acc2 * inv0 + bb0.y);   // ch 2cp+1
        float v10 = eluf(acc1 * inv1 + bb1.x);   // ch 2cp+64
        float v11 = eluf(acc3 * inv1 + bb1.y);   // ch 2cp+65
        o1b[n * 64 + cp]      = bfpair(v00, v01);
        o1b[n * 64 + 32 + cp] = bfpair(v10, v11);
        const float4* w2v4 = (const float4*)w2v;
        float4 wv0 = w2v4[cp];        // [2cp][0..1],[2cp+1][0..1]
        float4 wv1 = w2v4[32 + cp];   // [2cp+64][0..1],[2cp+65][0..1]
        float p0 = v00 * wv0.x + v01 * wv0.z + v10 * wv1.x + v11 * wv1.z;
        float p1 = v00 * wv0.y + v01 * wv0.w + v10 * wv1.y + v11 * wv1.w;
#pragma unroll
        for (int off = 1; off < 32; off <<= 1) {
            p0 += __shfl_xor(p0, off);
            p1 += __shfl_xor(p1, off);
        }
        if (cp == 0) { als2[n] = p0; ald2[n] = p1; }
    }
}

// ---------------- GEMM2 (MFMA): h2b = bf16( o1b @ (W2hi+W2lo) ), dword w = chs (w, w+16) ----------------
__global__ __launch_bounds__(256) void k_gemm2(const uint4* __restrict__ ob4,
                                               const float* __restrict__ W,
                                               uint* __restrict__ h2b) {
    __shared__ uint4 WH[512];           // Wt_hi[n 0..31][k] swizzled, 8 KB
    __shared__ uint4 WL[512];
    int t = threadIdx.x;
    uint* whw = (uint*)WH;
    uint* wlw = (uint*)WL;
    for (int it = 0; it < 4; ++it) {
        int u = it * 256 + t;
        int n = u & 31, kq = u >> 5;
        float w0 = W[(kq * 4 + 0) * 32 + n];
        float w1 = W[(kq * 4 + 1) * 32 + n];
        float w2 = W[(kq * 4 + 2) * 32 + n];
        float w3 = W[(kq * 4 + 3) * 32 + n];
        uint h0 = bfr(w0), h1 = bfr(w1), h2 = bfr(w2), h3 = bfr(w3);
        float l0 = w0 - __uint_as_float(h0 << 16);
        float l1 = w1 - __uint_as_float(h1 << 16);
        float l2 = w2 - __uint_as_float(h2 << 16);
        float l3 = w3 - __uint_as_float(h3 << 16);
        int word = n * 64 + (((kq >> 1) ^ (n & 7)) << 2) + (kq & 1) * 2;
        *(uint2*)&whw[word] = make_uint2(h0 | (h1 << 16), h2 | (h3 << 16));
        *(uint2*)&wlw[word] = make_uint2(bfr(l0) | (bfr(l1) << 16), bfr(l2) | (bfr(l3) << 16));
    }
    __syncthreads();
    int l = t & 63, wid = t >> 6;
    int lr = l & 15, lg = l >> 4;
    int rowb = blockIdx.x * 128 + wid * 32;
    f32x4 acc[2][2] = {};
#pragma unroll
    for (int ks = 0; ks < 4; ++ks) {
        uint4 av0 = ob4[(rowb + lr) * 16 + ks * 4 + lg];
        uint4 av1 = ob4[(rowb + 16 + lr) * 16 + ks * 4 + lg];
        bf16x8 a0 = *reinterpret_cast<bf16x8*>(&av0);
        bf16x8 a1 = *reinterpret_cast<bf16x8*>(&av1);
        int quw = ks * 4 + lg;
#pragma unroll
        for (int nt = 0; nt < 2; ++nt) {
            int n = nt * 16 + lr;
            int idx = n * 16 + (quw ^ (n & 7));
            bf16x8 bh = *reinterpret_cast<bf16x8*>(&WH[idx]);
            bf16x8 bl = *reinterpret_cast<bf16x8*>(&WL[idx]);
            acc[0][nt] = __builtin_amdgcn_mfma_f32_16x16x32_bf16(a0, bh, acc[0][nt], 0, 0, 0);
            acc[0][nt] = __builtin_amdgcn_mfma_f32_16x16x32_bf16(a0, bl, acc[0][nt], 0, 0, 0);
            acc[1][nt] = __builtin_amdgcn_mfma_f32_16x16x32_bf16(a1, bh, acc[1][nt], 0, 0, 0);
            acc[1][nt] = __builtin_amdgcn_mfma_f32_16x16x32_bf16(a1, bl, acc[1][nt], 0, 0, 0);
        }
    }
#pragma unroll
    for (int mt = 0; mt < 2; ++mt)
#pragma unroll
        for (int r = 0; r < 4; ++r) {
            int row = rowb + mt * 16 + 4 * lg + r;
            if (row < N_NODES)
                h2b[row * 16 + lr] = bfpair(acc[mt][0][r], acc[mt][1][r]);
        }
}

// ---------------- agg2: chunked LDS weight cache, quarter-wave per edge ----------------
__global__ __launch_bounds__(256) void k_agg2(const uint* __restrict__ h2b,
                                              const int* __restrict__ csr, const int* __restrict__ esrc,
                                              const float* __restrict__ als, const float* __restrict__ ald,
                                              const float* __restrict__ b2,
                                              float* __restrict__ o2) {
    __shared__ float wbuf[4][2][64];    // 2 KB
    int l = threadIdx.x & 63;
    int wv = threadIdx.x >> 6;
    int n = blockIdx.x * 4 + wv;
    int s = csr[n], e = csr[n + 1];
    int cp = l & 15, sub = l >> 4;
    float ad = ald[n];
    float acc0 = 0.f, acc1 = 0.f, ssum = 0.f;
    int buf = 0;
    for (int c0 = s; c0 < e; c0 += 64, buf ^= 1) {
        int cnt = min(64, e - c0);
        float* wb = wbuf[wv][buf];
        for (int j = l; j < cnt; j += 64) {
            int sa = esrc[c0 + j];
            float wgt = __expf(lrelu(als[sa] + ad));
            wb[j] = wgt;
            ssum += wgt;
        }
        for (int i = c0 + sub; i < c0 + cnt; i += 4) {
            int sa = esrc[i];
            float wgt = wb[i - c0];
            uint d = h2b[sa * 16 + cp];
            acc0 += wgt * bflo(d); acc1 += wgt * bfhi(d);
        }
    }
#pragma unroll
    for (int off = 1; off < 64; off <<= 1) ssum += __shfl_xor(ssum, off);
    acc0 += __shfl_xor(acc0, 16); acc1 += __shfl_xor(acc1, 16);
    acc0 += __shfl_xor(acc0, 32); acc1 += __shfl_xor(acc1, 32);
    if (l < 16) {
        float inv = 1.f / ssum;
        o2[n * 32 + cp]      = eluf(acc0 * inv + b2[cp]);
        o2[n * 32 + 16 + cp] = eluf(acc1 * inv + b2[16 + cp]);
    }
}

// ---------------- fused pool + final linear (inline boundary search) ----------------
__global__ __launch_bounds__(256) void k_poolfinal(const float* __restrict__ out2,
                                                   const int* __restrict__ batch,
                                                   const float* __restrict__ Wl,
                                                   const float* __restrict__ bl,
                                                   float* __restrict__ out) {
    __shared__ float red[4][32];
    __shared__ float pooled[32];
    int g = blockIdx.x;
    int s = 0, hi = N_NODES;
    while (s < hi) { int mid = (s + hi) >> 1; if (batch[mid] < g) s = mid + 1; else hi = mid; }
    int e = s; hi = N_NODES;
    while (e < hi) { int mid = (e + hi) >> 1; if (batch[mid] < g + 1) e = mid + 1; else hi = mid; }
    int t = threadIdx.x;
    int c = t & 31, r = t >> 5;
    float acc = 0.f;
    for (int i = s + r; i < e; i += 8)
        acc += out2[i * 32 + c];
    acc += __shfl_xor(acc, 32);
    if ((t & 63) < 32) red[t >> 6][c] = acc;
    __syncthreads();
    if (t < 32) {
        float v = red[0][t] + red[1][t] + red[2][t] + red[3][t];
        float cnt = fmaxf((float)(e - s), 1.f);
        pooled[t] = v / cnt;
    }
    __syncthreads();
    if (t < OUTC) {
        float a = 0.f;
        for (int cc = 0; cc < HIDC; cc++)
            a += pooled[cc] * Wl[cc * OUTC + t];
        out[g * OUTC + t] = a + bl[t];
    }
}

extern "C" void kernel_launch(void* const* d_in, const int* in_sizes, int n_in,
                              void* d_out, int out_size, void* d_ws, size_t ws_size,
                              hipStream_t stream) {
    (void)in_sizes; (void)n_in; (void)out_size; (void)ws_size;
    const float* x    = (const float*)d_in[0];
    const int*   ei   = (const int*)d_in[1];
    const int*   srcA = ei;
    const int*   dstA = ei + N_EDGES;
    const int*   batch = (const int*)d_in[2];
    const float* W1  = (const float*)d_in[3];
    const float* a1s = (const float*)d_in[4];
    const float* a1d = (const float*)d_in[5];
    const float* b1  = (const float*)d_in[6];
    const float* W2  = (const float*)d_in[7];
    const float* a2s = (const float*)d_in[8];
    const float* a2d = (const float*)d_in[9];
    const float* b2  = (const float*)d_in[10];
    const float* Wl  = (const float*)d_in[11];
    const float* bl  = (const float*)d_in[12];
    float* out = (float*)d_out;

    char* w = (char*)d_ws;
    auto alloc = [&](size_t bytes) -> void* {
        void* p = (void*)w;
        w += (bytes + 255) & ~(size_t)255;
        return p;
    };
    uint*  xb   = (uint*)alloc((size_t)NPAD * 64 * 4);       // x bf16, 12.85 MB
    uint*  h1b  = (uint*)alloc((size_t)N_NODES * 64 * 4);    // 12.8 MB
    uint*  o1b  = (uint*)alloc((size_t)NPAD * 64 * 4);       // 12.85 MB
    uint*  h2b  = (uint*)alloc((size_t)N_NODES * 16 * 4);    // 3.2 MB
    float* o2   = (float*)alloc((size_t)N_NODES * 32 * 4);   // 6.4 MB
    float* als1 = (float*)alloc((size_t)N_NODES * 4 * 4);
    float* ald1 = (float*)alloc((size_t)N_NODES * 4 * 4);
    float* als2 = (float*)alloc((size_t)N_NODES * 4);
    float* ald2 = (float*)alloc((size_t)N_NODES * 4);
    float* w_als = (float*)alloc(1024 * 4);
    float* w2v   = (float*)alloc(256 * 4);
    int*   indeg = (int*)alloc((size_t)N_NODES * 4);
    int*   csr   = (int*)alloc((size_t)(N_NODES + 1) * 4);
    int*   pos   = (int*)alloc((size_t)N_NODES * 4);
    int*   esrc  = (int*)alloc((size_t)EP * 4);
    int*   bsum  = (int*)alloc(256 * 4);

    int nb = (N_NODES + 255) / 256;      // 196
    int ncc = (N_EDGES + 2047) / 2048;   // count chunks: 391
    int nsc = (EP + 2047) / 2048;        // scatter chunks: 416

    hipMemsetAsync(indeg, 0, (size_t)N_NODES * 4, stream);
    k_count<<<ncc * NPART, 256, 0, stream>>>(dstA, indeg);
    k_scan1<<<nb, 256, 0, stream>>>(indeg, csr, bsum);
    k_scan2<<<1, 256, 0, stream>>>(bsum, nb);
    k_scan3<<<nb, 256, 0, stream>>>(indeg, csr, bsum, pos);
    k_scatter<<<nsc * NPART, 256, 0, stream>>>(srcA, dstA, pos, esrc);
    k_wprep<<<1, 256, 0, stream>>>(W1, a1s, a1d, W2, a2s, a2d, w_als, w2v);
    k_cvt<<<N_NODES / 8, 256, 0, stream>>>(x, w_als, (uint2*)xb, als1, ald1);
    k_gemm1<<<NPAD / 128, 256, 0, stream>>>((const uint4*)xb, W1, h1b);
    k_agg1<<<N_NODES / 4, 256, 0, stream>>>((const uint2*)h1b, csr, esrc, als1, ald1, b1, w2v,
                                            o1b, als2, ald2);
    k_gemm2<<<NPAD / 128, 256, 0, stream>>>((const uint4*)o1b, W2, h2b);
    k_agg2<<<N_NODES / 4, 256, 0, stream>>>(h2b, csr, esrc, als2, ald2, b2, o2);
    k_poolfinal<<<NGRAPH, 256, 0, stream>>>(o2, batch, Wl, bl, out);
}

// Round 9
// 235.636 us; speedup vs baseline: 1.6204x; 1.1232x over previous
//
#include <hip/hip_runtime.h>
#include <math.h>

#define N_NODES 50000
#define N_EDGES 800000
#define EP      (N_EDGES + N_NODES)   // edges incl. self loops
#define IN_CH   128
#define HIDC    32
#define HEADS   4
#define OUTC    10
#define NGRAPH  64
#define NEG_SLOPE 0.2f
#define NPAD    50176                  // 128-row padded node count
#define NPART   8
#define PRNG    (N_NODES / NPART)      // 6250 nodes per partition
#define LOG2E   1.44269504088896f

typedef unsigned int uint;
typedef __attribute__((ext_vector_type(8))) short bf16x8;
typedef __attribute__((ext_vector_type(4))) float f32x4;

__device__ __forceinline__ float lrelu(float x) { return x > 0.f ? x : NEG_SLOPE * x; }
__device__ __forceinline__ float eluf(float x)  { return x > 0.f ? x : __expf(x) - 1.f; }
__device__ __forceinline__ float exp2fast(float x) {   // 2^x, single v_exp_f32
    float r; asm("v_exp_f32 %0, %1" : "=v"(r) : "v"(x)); return r;
}

__device__ __forceinline__ uint bfr(float f) {                 // f32 -> bf16 bits (RNE)
    uint a = __float_as_uint(f);
    return (a + 0x7FFFu + ((a >> 16) & 1u)) >> 16;
}
__device__ __forceinline__ uint bfpair(float lo, float hi) { return bfr(lo) | (bfr(hi) << 16); }
__device__ __forceinline__ float bflo(uint d) { return __uint_as_float(d << 16); }
__device__ __forceinline__ float bfhi(uint d) { return __uint_as_float(d & 0xFFFF0000u); }

// ---------------- CSR build (dst-range partitioned: blockIdx%8 ~ XCD) ----------------
__global__ __launch_bounds__(256) void k_count(const int* __restrict__ dst, int* __restrict__ indeg) {
    int part = blockIdx.x & (NPART - 1);
    int base = (blockIdx.x >> 3) * 2048;
    int lo = part * PRNG;
#pragma unroll
    for (int it = 0; it < 8; ++it) {
        int e = base + it * 256 + threadIdx.x;
        if (e < N_EDGES) {
            int d = dst[e];
            if ((uint)(d - lo) < PRNG) atomicAdd(&indeg[d], 1);
        }
    }
}

// ---------------- parallel 3-stage scan (196 blocks) ----------------
__global__ void k_scan1(const int* __restrict__ indeg, int* __restrict__ incl, int* __restrict__ bsum) {
    __shared__ int s[256];
    int t = threadIdx.x;
    int i = blockIdx.x * 256 + t;
    int v = (i < N_NODES) ? indeg[i] + 1 : 0;   // +1 self loop
    s[t] = v; __syncthreads();
    for (int off = 1; off < 256; off <<= 1) {
        int x = (t >= off) ? s[t - off] : 0;
        __syncthreads();
        s[t] += x;
        __syncthreads();
    }
    if (i < N_NODES) incl[i] = s[t];
    if (t == 255) bsum[blockIdx.x] = s[255];
}

__global__ void k_scan2(int* __restrict__ bsum, int nb) {
    __shared__ int s[256];
    int t = threadIdx.x;
    int v = (t < nb) ? bsum[t] : 0;
    s[t] = v; __syncthreads();
    for (int off = 1; off < 256; off <<= 1) {
        int x = (t >= off) ? s[t - off] : 0;
        __syncthreads();
        s[t] += x;
        __syncthreads();
    }
    if (t < nb) bsum[t] = s[t] - v;   // exclusive
}

__global__ void k_scan3(const int* __restrict__ indeg, int* __restrict__ csr,
                        const int* __restrict__ boff, int* __restrict__ pos) {
    int i = blockIdx.x * 256 + threadIdx.x;
    if (i >= N_NODES) return;
    int inc = csr[i] + boff[i >> 8];
    int ex = inc - indeg[i] - 1;
    csr[i] = ex;
    pos[i] = ex;
    if (i == N_NODES - 1) csr[N_NODES] = inc;
}

__global__ __launch_bounds__(256) void k_scatter(const int* __restrict__ src, const int* __restrict__ dst,
                                                 int* __restrict__ pos, int* __restrict__ esrc) {
    int part = blockIdx.x & (NPART - 1);
    int base = (blockIdx.x >> 3) * 2048;
    int lo = part * PRNG;
#pragma unroll
    for (int it = 0; it < 8; ++it) {
        int e = base + it * 256 + threadIdx.x;
        if (e < EP) {
            int d = (e < N_EDGES) ? dst[e] : (e - N_EDGES);
            if ((uint)(d - lo) < PRNG) {
                int s = (e < N_EDGES) ? src[e] : d;
                int p = atomicAdd(&pos[d], 1);
                esrc[p] = s;
            }
        }
    }
}

// ---------------- weight prep (scaled by log2e for exp2 path) ----------------
__global__ void k_wprep(const float* __restrict__ W1,
                        const float* __restrict__ a1s, const float* __restrict__ a1d,
                        const float* __restrict__ W2,
                        const float* __restrict__ a2s, const float* __restrict__ a2d,
                        float* __restrict__ w_als, float* __restrict__ w2v) {
    int t = threadIdx.x;
    for (int it = 0; it < 4; ++it) {
        int u = it * 256 + t;           // 1024 units
        int i = u >> 3, j = u & 7;
        int head = j & 3;
        const float* vec = (j < 4) ? a1s : a1d;
        float s = 0.f;
        for (int c = 0; c < 32; ++c)
            s += W1[i * 128 + head * 32 + c] * vec[head * 32 + c];
        w_als[u] = s * LOG2E;
    }
    {
        int i = t >> 1, j = t & 1;
        const float* vec = j ? a2d : a2s;
        float s = 0.f;
        for (int c = 0; c < 32; ++c)
            s += W2[i * 32 + c] * vec[c];
        w2v[i * 2 + j] = s * LOG2E;
    }
}

// ---------------- cvt: x -> bf16 xb, + conv1 logits packed as head pairs ----------------
// als1p4[n] = {s0,s2,s1,s3}; ald1p4[n] = {d0,d2,d1,d3}  (float2 idx hh0 -> heads hh0,hh0+2)
__global__ __launch_bounds__(256) void k_cvt(const float* __restrict__ x,
                                             const float* __restrict__ w_als,
                                             uint2* __restrict__ xb2,
                                             float4* __restrict__ als1p4, float4* __restrict__ ald1p4) {
    __shared__ float wc[1024];          // column-major: wc[j*128 + ch]
    int t = threadIdx.x;
    for (int u = t; u < 1024; u += 256) {
        int ch = u >> 3, j = u & 7;
        wc[j * 128 + ch] = w_als[u];
    }
    __syncthreads();
    int n = blockIdx.x * 8 + (t >> 5);
    int cp = t & 31;
    float4 xv = *(const float4*)&x[n * 128 + cp * 4];
    xb2[n * 32 + cp] = make_uint2(bfpair(xv.x, xv.y), bfpair(xv.z, xv.w));
    float p[8];
#pragma unroll
    for (int j = 0; j < 8; ++j) {
        float4 w = *(const float4*)&wc[j * 128 + cp * 4];
        p[j] = xv.x * w.x + xv.y * w.y + xv.z * w.z + xv.w * w.w;
    }
#pragma unroll
    for (int off = 1; off < 32; off <<= 1) {
#pragma unroll
        for (int j = 0; j < 8; ++j) p[j] += __shfl_xor(p[j], off);
    }
    if (cp == 0) {
        float4 s = {p[0], p[2], p[1], p[3]};
        float4 d = {p[4], p[6], p[5], p[7]};
        als1p4[n] = s;
        ald1p4[n] = d;
    }
}

// ---------------- GEMM1 (MFMA): h1b = bf16( xb @ (W1hi+W1lo) ), dword w = chs (w, w+64) ----------------
__global__ __launch_bounds__(256) void k_gemm1(const uint4* __restrict__ xb4,
                                               const float* __restrict__ W,
                                               uint* __restrict__ h1b) {
    __shared__ uint4 WH[2048];          // Wt_hi[n][k] swizzled, 32 KB
    __shared__ uint4 WL[2048];          // Wt_lo
    int t = threadIdx.x;
    uint* whw = (uint*)WH;
    uint* wlw = (uint*)WL;
    for (int it = 0; it < 16; ++it) {
        int u = it * 256 + t;
        int n = u & 127, kq = u >> 7;   // kq: 4-wide k group (0..31)
        float w0 = W[(kq * 4 + 0) * 128 + n];
        float w1 = W[(kq * 4 + 1) * 128 + n];
        float w2 = W[(kq * 4 + 2) * 128 + n];
        float w3 = W[(kq * 4 + 3) * 128 + n];
        uint h0 = bfr(w0), h1 = bfr(w1), h2 = bfr(w2), h3 = bfr(w3);
        float l0 = w0 - __uint_as_float(h0 << 16);
        float l1 = w1 - __uint_as_float(h1 << 16);
        float l2 = w2 - __uint_as_float(h2 << 16);
        float l3 = w3 - __uint_as_float(h3 << 16);
        int word = n * 64 + (((kq >> 1) ^ (n & 7)) << 2) + (kq & 1) * 2;
        *(uint2*)&whw[word] = make_uint2(h0 | (h1 << 16), h2 | (h3 << 16));
        *(uint2*)&wlw[word] = make_uint2(bfr(l0) | (bfr(l1) << 16), bfr(l2) | (bfr(l3) << 16));
    }
    __syncthreads();
    int l = t & 63, wid = t >> 6;
    int lr = l & 15, lg = l >> 4;
    int rowb = blockIdx.x * 128 + wid * 32;
    f32x4 acc[2][8] = {};
#pragma unroll
    for (int ks = 0; ks < 4; ++ks) {
        uint4 av0 = xb4[(rowb + lr) * 16 + ks * 4 + lg];
        uint4 av1 = xb4[(rowb + 16 + lr) * 16 + ks * 4 + lg];
        bf16x8 a0 = *reinterpret_cast<bf16x8*>(&av0);
        bf16x8 a1 = *reinterpret_cast<bf16x8*>(&av1);
        int quw = ks * 4 + lg;
#pragma unroll
        for (int nt = 0; nt < 8; ++nt) {
            int n = nt * 16 + lr;
            int idx = n * 16 + (quw ^ (n & 7));
            bf16x8 bh = *reinterpret_cast<bf16x8*>(&WH[idx]);
            bf16x8 bl = *reinterpret_cast<bf16x8*>(&WL[idx]);
            acc[0][nt] = __builtin_amdgcn_mfma_f32_16x16x32_bf16(a0, bh, acc[0][nt], 0, 0, 0);
            acc[0][nt] = __builtin_amdgcn_mfma_f32_16x16x32_bf16(a0, bl, acc[0][nt], 0, 0, 0);
            acc[1][nt] = __builtin_amdgcn_mfma_f32_16x16x32_bf16(a1, bh, acc[1][nt], 0, 0, 0);
            acc[1][nt] = __builtin_amdgcn_mfma_f32_16x16x32_bf16(a1, bl, acc[1][nt], 0, 0, 0);
        }
    }
#pragma unroll
    for (int mt = 0; mt < 2; ++mt)
#pragma unroll
        for (int nt = 0; nt < 4; ++nt)
#pragma unroll
            for (int r = 0; r < 4; ++r) {
                int row = rowb + mt * 16 + 4 * lg + r;
                if (row < N_NODES)
                    h1b[row * 64 + nt * 16 + lr] = bfpair(acc[mt][nt][r], acc[mt][nt + 4][r]);
            }
}

// ---------------- agg1: single pass, quarter-wave per edge (4 edges in flight) ----------------
// lane = sub*16 + cp4; edge i = c+sub; lane covers dwords 4cp4..4cp4+3 = chs {4cp4+j, 4cp4+j+64}
__global__ __launch_bounds__(256) void k_agg1(const uint4* __restrict__ h1b4,
                                              const int* __restrict__ csr, const int* __restrict__ esrc,
                                              const float2* __restrict__ als1p, const float2* __restrict__ ald1p,
                                              const float* __restrict__ b1,
                                              const float* __restrict__ w2v,
                                              uint2* __restrict__ o1b2,
                                              float* __restrict__ als2, float* __restrict__ ald2) {
    int l = threadIdx.x & 63;
    int wv = threadIdx.x >> 6;
    int n = blockIdx.x * 4 + wv;
    int s = csr[n], e = csr[n + 1];
    int sub = l >> 4, cp4 = l & 15, hh0 = cp4 >> 3;   // heads (hh0, hh0+2)
    float2 ad = ald1p[n * 2 + hh0];
    float aL0=0,aL1=0,aL2=0,aL3=0,aH0=0,aH1=0,aH2=0,aH3=0, ss0=0, ss1=0;
#pragma unroll 2
    for (int i = s + sub; i < e; i += 4) {
        int sa = esrc[i];
        float2 av = als1p[sa * 2 + hh0];
        float z0 = av.x + ad.x, z1 = av.y + ad.y;
        float e0 = exp2fast(fmaxf(z0, NEG_SLOPE * z0));
        float e1 = exp2fast(fmaxf(z1, NEG_SLOPE * z1));
        uint4 d = h1b4[sa * 16 + cp4];
        ss0 += e0; ss1 += e1;
        aL0 += e0 * bflo(d.x); aH0 += e1 * bfhi(d.x);
        aL1 += e0 * bflo(d.y); aH1 += e1 * bfhi(d.y);
        aL2 += e0 * bflo(d.z); aH2 += e1 * bfhi(d.z);
        aL3 += e0 * bflo(d.w); aH3 += e1 * bfhi(d.w);
    }
    // reduce across subs (lane bits 4,5)
    ss0 += __shfl_xor(ss0, 16); ss0 += __shfl_xor(ss0, 32);
    ss1 += __shfl_xor(ss1, 16); ss1 += __shfl_xor(ss1, 32);
    aL0 += __shfl_xor(aL0, 16); aL0 += __shfl_xor(aL0, 32);
    aL1 += __shfl_xor(aL1, 16); aL1 += __shfl_xor(aL1, 32);
    aL2 += __shfl_xor(aL2, 16); aL2 += __shfl_xor(aL2, 32);
    aL3 += __shfl_xor(aL3, 16); aL3 += __shfl_xor(aL3, 32);
    aH0 += __shfl_xor(aH0, 16); aH0 += __shfl_xor(aH0, 32);
    aH1 += __shfl_xor(aH1, 16); aH1 += __shfl_xor(aH1, 32);
    aH2 += __shfl_xor(aH2, 16); aH2 += __shfl_xor(aH2, 32);
    aH3 += __shfl_xor(aH3, 16); aH3 += __shfl_xor(aH3, 32);
    if (sub == 0) {
        float inv0 = 1.f / ss0, inv1 = 1.f / ss1;
        float4 bbL = *(const float4*)&b1[cp4 * 4];
        float4 bbH = *(const float4*)&b1[64 + cp4 * 4];
        float v0 = eluf(aL0 * inv0 + bbL.x);
        float v1 = eluf(aL1 * inv0 + bbL.y);
        float v2 = eluf(aL2 * inv0 + bbL.z);
        float v3 = eluf(aL3 * inv0 + bbL.w);
        float u0 = eluf(aH0 * inv1 + bbH.x);
        float u1 = eluf(aH1 * inv1 + bbH.y);
        float u2 = eluf(aH2 * inv1 + bbH.z);
        float u3 = eluf(aH3 * inv1 + bbH.w);
        o1b2[n * 32 + cp4]      = make_uint2(bfpair(v0, v1), bfpair(v2, v3));
        o1b2[n * 32 + 16 + cp4] = make_uint2(bfpair(u0, u1), bfpair(u2, u3));
        // conv2 logits: channels 4cp4..4cp4+3 and 64+4cp4..64+4cp4+3
        const float4* w2 = (const float4*)w2v;
        float4 wa = w2[2 * cp4], wb = w2[2 * cp4 + 1];
        float4 wc = w2[32 + 2 * cp4], wd = w2[32 + 2 * cp4 + 1];
        float p0 = v0*wa.x + v1*wa.z + v2*wb.x + v3*wb.z + u0*wc.x + u1*wc.z + u2*wd.x + u3*wd.z;
        float p1 = v0*wa.y + v1*wa.w + v2*wb.y + v3*wb.w + u0*wc.y + u1*wc.w + u2*wd.y + u3*wd.w;
        p0 += __shfl_xor(p0, 1); p0 += __shfl_xor(p0, 2);
        p0 += __shfl_xor(p0, 4); p0 += __shfl_xor(p0, 8);
        p1 += __shfl_xor(p1, 1); p1 += __shfl_xor(p1, 2);
        p1 += __shfl_xor(p1, 4); p1 += __shfl_xor(p1, 8);
        if (cp4 == 0) { als2[n] = p0; ald2[n] = p1; }
    }
}

// ---------------- GEMM2 (MFMA): h2b = bf16( o1b @ (W2hi+W2lo) ), dword w = chs (w, w+16) ----------------
__global__ __launch_bounds__(256) void k_gemm2(const uint4* __restrict__ ob4,
                                               const float* __restrict__ W,
                                               uint* __restrict__ h2b) {
    __shared__ uint4 WH[512];           // Wt_hi[n 0..31][k] swizzled, 8 KB
    __shared__ uint4 WL[512];
    int t = threadIdx.x;
    uint* whw = (uint*)WH;
    uint* wlw = (uint*)WL;
    for (int it = 0; it < 4; ++it) {
        int u = it * 256 + t;
        int n = u & 31, kq = u >> 5;
        float w0 = W[(kq * 4 + 0) * 32 + n];
        float w1 = W[(kq * 4 + 1) * 32 + n];
        float w2 = W[(kq * 4 + 2) * 32 + n];
        float w3 = W[(kq * 4 + 3) * 32 + n];
        uint h0 = bfr(w0), h1 = bfr(w1), h2 = bfr(w2), h3 = bfr(w3);
        float l0 = w0 - __uint_as_float(h0 << 16);
        float l1 = w1 - __uint_as_float(h1 << 16);
        float l2 = w2 - __uint_as_float(h2 << 16);
        float l3 = w3 - __uint_as_float(h3 << 16);
        int word = n * 64 + (((kq >> 1) ^ (n & 7)) << 2) + (kq & 1) * 2;
        *(uint2*)&whw[word] = make_uint2(h0 | (h1 << 16), h2 | (h3 << 16));
        *(uint2*)&wlw[word] = make_uint2(bfr(l0) | (bfr(l1) << 16), bfr(l2) | (bfr(l3) << 16));
    }
    __syncthreads();
    int l = t & 63, wid = t >> 6;
    int lr = l & 15, lg = l >> 4;
    int rowb = blockIdx.x * 128 + wid * 32;
    f32x4 acc[2][2] = {};
#pragma unroll
    for (int ks = 0; ks < 4; ++ks) {
        uint4 av0 = ob4[(rowb + lr) * 16 + ks * 4 + lg];
        uint4 av1 = ob4[(rowb + 16 + lr) * 16 + ks * 4 + lg];
        bf16x8 a0 = *reinterpret_cast<bf16x8*>(&av0);
        bf16x8 a1 = *reinterpret_cast<bf16x8*>(&av1);
        int quw = ks * 4 + lg;
#pragma unroll
        for (int nt = 0; nt < 2; ++nt) {
            int n = nt * 16 + lr;
            int idx = n * 16 + (quw ^ (n & 7));
            bf16x8 bh = *reinterpret_cast<bf16x8*>(&WH[idx]);
            bf16x8 bl = *reinterpret_cast<bf16x8*>(&WL[idx]);
            acc[0][nt] = __builtin_amdgcn_mfma_f32_16x16x32_bf16(a0, bh, acc[0][nt], 0, 0, 0);
            acc[0][nt] = __builtin_amdgcn_mfma_f32_16x16x32_bf16(a0, bl, acc[0][nt], 0, 0, 0);
            acc[1][nt] = __builtin_amdgcn_mfma_f32_16x16x32_bf16(a1, bh, acc[1][nt], 0, 0, 0);
            acc[1][nt] = __builtin_amdgcn_mfma_f32_16x16x32_bf16(a1, bl, acc[1][nt], 0, 0, 0);
        }
    }
#pragma unroll
    for (int mt = 0; mt < 2; ++mt)
#pragma unroll
        for (int r = 0; r < 4; ++r) {
            int row = rowb + mt * 16 + 4 * lg + r;
            if (row < N_NODES)
                h2b[row * 16 + lr] = bfpair(acc[mt][0][r], acc[mt][1][r]);
        }
}

// ---------------- agg2: single pass, eighth-wave per edge (8 edges in flight) ----------------
__global__ __launch_bounds__(256) void k_agg2(const uint2* __restrict__ h2b2,
                                              const int* __restrict__ csr, const int* __restrict__ esrc,
                                              const float* __restrict__ als, const float* __restrict__ ald,
                                              const float* __restrict__ b2,
                                              float* __restrict__ o2) {
    int l = threadIdx.x & 63;
    int wv = threadIdx.x >> 6;
    int n = blockIdx.x * 4 + wv;
    int s = csr[n], e = csr[n + 1];
    int sub = l >> 3, cp8 = l & 7;       // dwords 2cp8, 2cp8+1 -> chs {2cp8(+1), 2cp8(+1)+16}
    float ad = ald[n];
    float a0 = 0, a1 = 0, a2 = 0, a3 = 0, ss = 0;
#pragma unroll 2
    for (int i = s + sub; i < e; i += 8) {
        int sa = esrc[i];
        float z = als[sa] + ad;
        float wgt = exp2fast(fmaxf(z, NEG_SLOPE * z));
        uint2 d = h2b2[sa * 8 + cp8];
        ss += wgt;
        a0 += wgt * bflo(d.x); a1 += wgt * bfhi(d.x);
        a2 += wgt * bflo(d.y); a3 += wgt * bfhi(d.y);
    }
    ss += __shfl_xor(ss, 8); ss += __shfl_xor(ss, 16); ss += __shfl_xor(ss, 32);
    a0 += __shfl_xor(a0, 8); a0 += __shfl_xor(a0, 16); a0 += __shfl_xor(a0, 32);
    a1 += __shfl_xor(a1, 8); a1 += __shfl_xor(a1, 16); a1 += __shfl_xor(a1, 32);
    a2 += __shfl_xor(a2, 8); a2 += __shfl_xor(a2, 16); a2 += __shfl_xor(a2, 32);
    a3 += __shfl_xor(a3, 8); a3 += __shfl_xor(a3, 16); a3 += __shfl_xor(a3, 32);
    if (sub == 0) {
        float inv = 1.f / ss;
        int c = 2 * cp8;
        float2 lo = { eluf(a0 * inv + b2[c]),      eluf(a2 * inv + b2[c + 1]) };
        float2 hi = { eluf(a1 * inv + b2[c + 16]), eluf(a3 * inv + b2[c + 17]) };
        *(float2*)&o2[n * 32 + c]      = lo;
        *(float2*)&o2[n * 32 + 16 + c] = hi;
    }
}

// ---------------- fused pool + final linear (inline boundary search) ----------------
__global__ __launch_bounds__(256) void k_poolfinal(const float* __restrict__ out2,
                                                   const int* __restrict__ batch,
                                                   const float* __restrict__ Wl,
                                                   const float* __restrict__ bl,
                                                   float* __restrict__ out) {
    __shared__ float red[4][32];
    __shared__ float pooled[32];
    int g = blockIdx.x;
    int s = 0, hi = N_NODES;
    while (s < hi) { int mid = (s + hi) >> 1; if (batch[mid] < g) s = mid + 1; else hi = mid; }
    int e = s; hi = N_NODES;
    while (e < hi) { int mid = (e + hi) >> 1; if (batch[mid] < g + 1) e = mid + 1; else hi = mid; }
    int t = threadIdx.x;
    int c = t & 31, r = t >> 5;
    float acc = 0.f;
    for (int i = s + r; i < e; i += 8)
        acc += out2[i * 32 + c];
    acc += __shfl_xor(acc, 32);
    if ((t & 63) < 32) red[t >> 6][c] = acc;
    __syncthreads();
    if (t < 32) {
        float v = red[0][t] + red[1][t] + red[2][t] + red[3][t];
        float cnt = fmaxf((float)(e - s), 1.f);
        pooled[t] = v / cnt;
    }
    __syncthreads();
    if (t < OUTC) {
        float a = 0.f;
        for (int cc = 0; cc < HIDC; cc++)
            a += pooled[cc] * Wl[cc * OUTC + t];
        out[g * OUTC + t] = a + bl[t];
    }
}

extern "C" void kernel_launch(void* const* d_in, const int* in_sizes, int n_in,
                              void* d_out, int out_size, void* d_ws, size_t ws_size,
                              hipStream_t stream) {
    (void)in_sizes; (void)n_in; (void)out_size; (void)ws_size;
    const float* x    = (const float*)d_in[0];
    const int*   ei   = (const int*)d_in[1];
    const int*   srcA = ei;
    const int*   dstA = ei + N_EDGES;
    const int*   batch = (const int*)d_in[2];
    const float* W1  = (const float*)d_in[3];
    const float* a1s = (const float*)d_in[4];
    const float* a1d = (const float*)d_in[5];
    const float* b1  = (const float*)d_in[6];
    const float* W2  = (const float*)d_in[7];
    const float* a2s = (const float*)d_in[8];
    const float* a2d = (const float*)d_in[9];
    const float* b2  = (const float*)d_in[10];
    const float* Wl  = (const float*)d_in[11];
    const float* bl  = (const float*)d_in[12];
    float* out = (float*)d_out;

    char* w = (char*)d_ws;
    auto alloc = [&](size_t bytes) -> void* {
        void* p = (void*)w;
        w += (bytes + 255) & ~(size_t)255;
        return p;
    };
    uint*  xb   = (uint*)alloc((size_t)NPAD * 64 * 4);       // x bf16, 12.85 MB
    uint*  h1b  = (uint*)alloc((size_t)N_NODES * 64 * 4);    // 12.8 MB
    uint*  o1b  = (uint*)alloc((size_t)NPAD * 64 * 4);       // 12.85 MB
    uint*  h2b  = (uint*)alloc((size_t)N_NODES * 16 * 4);    // 3.2 MB
    float* o2   = (float*)alloc((size_t)N_NODES * 32 * 4);   // 6.4 MB
    float* als1 = (float*)alloc((size_t)N_NODES * 4 * 4);
    float* ald1 = (float*)alloc((size_t)N_NODES * 4 * 4);
    float* als2 = (float*)alloc((size_t)N_NODES * 4);
    float* ald2 = (float*)alloc((size_t)N_NODES * 4);
    float* w_als = (float*)alloc(1024 * 4);
    float* w2v   = (float*)alloc(256 * 4);
    int*   indeg = (int*)alloc((size_t)N_NODES * 4);
    int*   csr   = (int*)alloc((size_t)(N_NODES + 1) * 4);
    int*   pos   = (int*)alloc((size_t)N_NODES * 4);
    int*   esrc  = (int*)alloc((size_t)EP * 4);
    int*   bsum  = (int*)alloc(256 * 4);

    int nb = (N_NODES + 255) / 256;      // 196
    int ncc = (N_EDGES + 2047) / 2048;   // count chunks: 391
    int nsc = (EP + 2047) / 2048;        // scatter chunks: 416

    hipMemsetAsync(indeg, 0, (size_t)N_NODES * 4, stream);
    k_count<<<ncc * NPART, 256, 0, stream>>>(dstA, indeg);
    k_scan1<<<nb, 256, 0, stream>>>(indeg, csr, bsum);
    k_scan2<<<1, 256, 0, stream>>>(bsum, nb);
    k_scan3<<<nb, 256, 0, stream>>>(indeg, csr, bsum, pos);
    k_scatter<<<nsc * NPART, 256, 0, stream>>>(srcA, dstA, pos, esrc);
    k_wprep<<<1, 256, 0, stream>>>(W1, a1s, a1d, W2, a2s, a2d, w_als, w2v);
    k_cvt<<<N_NODES / 8, 256, 0, stream>>>(x, w_als, (uint2*)xb, (float4*)als1, (float4*)ald1);
    k_gemm1<<<NPAD / 128, 256, 0, stream>>>((const uint4*)xb, W1, h1b);
    k_agg1<<<N_NODES / 4, 256, 0, stream>>>((const uint4*)h1b, csr, esrc,
                                            (const float2*)als1, (const float2*)ald1, b1, w2v,
                                            (uint2*)o1b, als2, ald2);
    k_gemm2<<<NPAD / 128, 256, 0, stream>>>((const uint4*)o1b, W2, h2b);
    k_agg2<<<N_NODES / 4, 256, 0, stream>>>((const uint2*)h2b, csr, esrc, als2, ald2, b2, o2);
    k_poolfinal<<<NGRAPH, 256, 0, stream>>>(o2, batch, Wl, bl, out);
}